// Round 3
// baseline (395.248 us; speedup 1.0000x reference)
//
#include <hip/hip_runtime.h>
#include <hip/hip_bf16.h>
#include <cstdint>

// ---------------------------------------------------------------------------
// TempoSpikeSelfAttention on MI355X (gfx950), bf16-MFMA pipeline.
//   dims: T=4 B=4 N=1024 D=768 H=12 Dh=64 -> M = T*B*N = 16384 rows
// Pipeline:
//   1. cast x, Wq|Wk|Wv (concat), Wo to bf16
//   2. QKV GEMM (m97 structure): QKV[16384, 2304] bf16, bias fused
//   3. transpose V -> Vt[(tb*12+h)*64 + d][1024]  (per-head d-major)
//   4. attn32 v3: 256 q/block, wave = 2 q-subtiles of 32; K/V staged via
//      global_load_lds into XOR-swizzled packed double buffers (1 barrier/iter,
//      prefetch overlaps compute); K/V frags hoisted across q-subtiles;
//      S^T = K Q^T (mfma 32x32x16), relu, b64-packed P (wave-private LDS),
//      octx += P V, L1-normalize at end.
//   5. O GEMM: out = CTX @ Wo^T + bo  -> fp32 d_out
// ---------------------------------------------------------------------------

typedef __attribute__((ext_vector_type(8))) short short8;     // 8 bf16 = 4 VGPR
typedef __attribute__((ext_vector_type(4))) float float4v;    // 16x16 acc
typedef __attribute__((ext_vector_type(16))) float float16v;  // 32x32 acc

__device__ __forceinline__ unsigned short f2bf(float f) {
  unsigned int u = __float_as_uint(f);
  u = (u + 0x7fffu + ((u >> 16) & 1u)) >> 16;   // RNE
  return (unsigned short)u;
}

// pack two f32 -> two bf16 (round-half-away) in one v_perm_b32
__device__ __forceinline__ unsigned int pkbf(float a, float b) {
  unsigned int ua = __float_as_uint(a) + 0x8000u;
  unsigned int ub = __float_as_uint(b) + 0x8000u;
  return __builtin_amdgcn_perm(ub, ua, 0x07060302u);  // [bf(a) lo16 | bf(b) hi16]
}

// async global->LDS, 16B per lane; LDS dest = wave-uniform base + lane*16
__device__ __forceinline__ void gld_lds16(const void* g, void* lds) {
  __builtin_amdgcn_global_load_lds(
      (__attribute__((address_space(1))) void*)(uintptr_t)g,
      (__attribute__((address_space(3))) void*)(uint32_t)(uintptr_t)lds,
      16, 0, 0);
}

// ---------------------------------------------------------------------------
__global__ __launch_bounds__(256) void cast4(const float* __restrict__ src,
                                             unsigned short* __restrict__ dst,
                                             int n4) {
  int i = blockIdx.x * 256 + threadIdx.x;
  if (i >= n4) return;
  float4 f = reinterpret_cast<const float4*>(src)[i];
  ushort4 o;
  o.x = f2bf(f.x); o.y = f2bf(f.y); o.z = f2bf(f.z); o.w = f2bf(f.w);
  reinterpret_cast<ushort4*>(dst)[i] = o;
}

// ---------------------------------------------------------------------------
// C[i,j] = sum_k A[i,k] * Bt[j,k] + bias[j].  K=768 fixed. 128x128 tile, BK=32.
// 4 waves in 2x2, each 64x64 (4x4 mfma 16x16x32 tiles).
template <bool OUT_BF16>
__global__ __launch_bounds__(256) void gemm_bt(
    const unsigned short* __restrict__ A,   // [M,768] bf16
    const unsigned short* __restrict__ Bt,  // [N,768] bf16
    unsigned short* __restrict__ Cb,        // bf16 out [M,N]
    float* __restrict__ Cf,                 // f32 out  [M,N]
    const float* __restrict__ b0, const float* __restrict__ b1,
    const float* __restrict__ b2, int N) {
  constexpr int K = 768;
  __shared__ unsigned short As[128 * 32];   // packed: row stride 32 el (64 B)
  __shared__ unsigned short Bs[128 * 32];

  const int tid = threadIdx.x;
  const int lane = tid & 63;
  const int w = tid >> 6;
  const int wrow = w >> 1, wcol = w & 1;
  const int l15 = lane & 15, quad = lane >> 4;
  const int i0 = blockIdx.y * 128, j0 = blockIdx.x * 128;

  const unsigned short* ga = A + (size_t)(i0 + 32 * w + (lane >> 2)) * K + (lane & 3) * 8;
  const unsigned short* gb = Bt + (size_t)(j0 + 32 * w + (lane >> 2)) * K + (lane & 3) * 8;

  float4v acc[4][4];
#pragma unroll
  for (int a = 0; a < 4; ++a)
#pragma unroll
    for (int b = 0; b < 4; ++b) acc[a][b] = float4v{0.f, 0.f, 0.f, 0.f};

#pragma unroll 1
  for (int kt = 0; kt < K / 32; ++kt) {
    const unsigned short* pa = ga + kt * 32;
    const unsigned short* pb = gb + kt * 32;
    gld_lds16(pa, &As[(32 * w) * 32]);
    gld_lds16(pa + 16 * K, &As[(32 * w + 16) * 32]);
    gld_lds16(pb, &Bs[(32 * w) * 32]);
    gld_lds16(pb + 16 * K, &Bs[(32 * w + 16) * 32]);
    __syncthreads();   // drains vmcnt before barrier -> LDS tiles ready

    short8 af[4], bfr[4];
#pragma unroll
    for (int a = 0; a < 4; ++a)
      af[a] = *(const short8*)&As[(wrow * 64 + a * 16 + l15) * 32 + quad * 8];
#pragma unroll
    for (int b = 0; b < 4; ++b)
      bfr[b] = *(const short8*)&Bs[(wcol * 64 + b * 16 + l15) * 32 + quad * 8];
#pragma unroll
    for (int a = 0; a < 4; ++a)
#pragma unroll
      for (int b = 0; b < 4; ++b)
        acc[a][b] = __builtin_amdgcn_mfma_f32_16x16x32_bf16(af[a], bfr[b], acc[a][b], 0, 0, 0);
    __syncthreads();   // all reads done before next stage overwrites
  }

  const int sel = j0 / 768;
  const float* bp = (sel == 0) ? b0 : ((sel == 1) ? b1 : b2);
#pragma unroll
  for (int a = 0; a < 4; ++a) {
    const int row0 = i0 + wrow * 64 + a * 16 + quad * 4;
#pragma unroll
    for (int b = 0; b < 4; ++b) {
      const int col = j0 + wcol * 64 + b * 16 + l15;
      const float bias = bp[col - sel * 768];
#pragma unroll
      for (int r = 0; r < 4; ++r) {
        const float v = acc[a][b][r] + bias;
        if (OUT_BF16)
          Cb[(size_t)(row0 + r) * N + col] = f2bf(v);
        else
          Cf[(size_t)(row0 + r) * N + col] = v;
      }
    }
  }
}

// ---------------------------------------------------------------------------
// Vt[(tb*12+h)*64 + d][n] = QKV[(tb*1024+n)*2304 + 1536 + h*64 + d]
__global__ __launch_bounds__(256) void transpose_v(
    const unsigned short* __restrict__ qkv, unsigned short* __restrict__ vt) {
  __shared__ unsigned short T[64 * 72];
  const int bz = blockIdx.x;        // 192*16
  const int nt = bz & 15;
  const int tbh = bz >> 4;
  const int tb = tbh / 12, h = tbh % 12;
  const int tid = threadIdx.x;
#pragma unroll
  for (int it = 0; it < 2; ++it) {
    int c = tid + it * 256;
    int row = c >> 3, d0 = (c & 7) * 8;
    const unsigned short* g =
        qkv + (size_t)(tb * 1024 + nt * 64 + row) * 2304 + 1536 + h * 64 + d0;
    *(uint4*)&T[row * 72 + d0] = *(const uint4*)g;
  }
  __syncthreads();
#pragma unroll
  for (int it = 0; it < 2; ++it) {
    int c = tid + it * 256;
    int d = c >> 3, n0 = (c & 7) * 8;
    unsigned short tmp[8];
#pragma unroll
    for (int i = 0; i < 8; ++i) tmp[i] = T[(n0 + i) * 72 + d];
    *(uint4*)&vt[((size_t)(tb * 12 + h) * 64 + d) * 1024 + nt * 64 + n0] =
        *(uint4*)tmp;
  }
}

// ---------------------------------------------------------------------------
// Attention v3, 32x32x16 MFMA. Block = (qt in 4, tbh in 192), 256 thr = 4 waves.
// Wave w owns q rows [qt*256 + w*64, +64) as 2 subtiles of 32 (qs).
// K/V tiles: packed 64x64 bf16 (row = kv for K, row = d for V), 16B blocks
// XOR-swizzled (block c stored at c ^ (row&7)) to break bank aliasing, staged
// via global_load_lds into double buffers; ONE barrier per kv-iter, prefetch
// of kv+1 issued right after the barrier (drained by next iter's barrier).
__global__ __launch_bounds__(256, 3) void attn32(
    const unsigned short* __restrict__ qkv,  // [16384, 2304] bf16
    const unsigned short* __restrict__ vt,   // [(tbh)*64 + d][1024] bf16
    unsigned short* __restrict__ ctx) {      // [16384, 768] bf16
  __shared__ unsigned short Ks[2][64 * 64];  // 8 KiB each
  __shared__ unsigned short Vs[2][64 * 64];
  __shared__ unsigned short Pb[4 * 32 * 72]; // per-wave P, stride 72 (144 B)

  const int qt = blockIdx.x;                 // 4 tiles of 256 q-rows
  const int tbh = blockIdx.y;
  const int tb = tbh / 12, h = tbh % 12;
  const int tid = threadIdx.x, lane = tid & 63, w = tid >> 6;
  const int l31 = lane & 31, hl = lane >> 5;

  // ---- Q fragments: one-time scattered global loads (no LDS round-trip) ----
  short8 qf[2][4];   // [qs][kc]: Q[q = qt*256+w*64+qs*32+l31][kc*16+hl*8 ..+8)
#pragma unroll
  for (int qs = 0; qs < 2; ++qs) {
    const size_t qrow = (size_t)(tb * 1024 + qt * 256 + w * 64 + qs * 32 + l31);
#pragma unroll
    for (int kc = 0; kc < 4; ++kc)
      qf[qs][kc] =
          *(const short8*)(qkv + qrow * 2304 + h * 64 + kc * 16 + hl * 8);
  }

  // staging geometry: wave w covers tile rows [w*16, w*16+16), 2 calls of 8 rows
  const int sr = (lane >> 3);        // row within 8-row group
  const int sblk = lane & 7;         // 16B block position in LDS row
  unsigned short* PW = &Pb[w * 32 * 72];

  float16v octx[2][2];
#pragma unroll
  for (int qs = 0; qs < 2; ++qs)
#pragma unroll
    for (int dt = 0; dt < 2; ++dt)
#pragma unroll
      for (int i = 0; i < 16; ++i) octx[qs][dt][i] = 0.f;
  float den[2] = {0.f, 0.f};

  auto stage = [&](int kv, int buf) {
#pragma unroll
    for (int t = 0; t < 2; ++t) {
      const int r = w * 16 + t * 8 + sr;
      const int c = sblk ^ (r & 7);          // swizzled source block
      gld_lds16(qkv + (size_t)(tb * 1024 + kv * 64 + r) * 2304 + 768 + h * 64 + c * 8,
                &Ks[buf][(w * 16 + t * 8) * 64]);
      gld_lds16(vt + ((size_t)tbh * 64 + r) * 1024 + kv * 64 + c * 8,
                &Vs[buf][(w * 16 + t * 8) * 64]);
    }
  };

  stage(0, 0);

#pragma unroll 1
  for (int kv = 0; kv < 16; ++kv) {
    const int cur = kv & 1;
    __syncthreads();                 // cur tiles ready (drains prefetch vmcnt)
    if (kv < 15) stage(kv + 1, cur ^ 1);   // overlaps with compute below

    // hoist V frags (shared across both q-subtiles)
    short8 vf[2][4];   // [dt][kc]: V[kv_el = kc*16+hl*8+j][d = dt*32+l31]
#pragma unroll
    for (int dt = 0; dt < 2; ++dt) {
      const int r = dt * 32 + l31;
#pragma unroll
      for (int kc = 0; kc < 4; ++kc)
        vf[dt][kc] =
            *(const short8*)&Vs[cur][r * 64 + (((kc * 2 + hl) ^ (r & 7)) * 8)];
    }

#pragma unroll
    for (int qs = 0; qs < 2; ++qs) {
      // S^T = K Q^T: 2 kv-local 32-row tiles
#pragma unroll
      for (int mt = 0; mt < 2; ++mt) {
        float16v st;
#pragma unroll
        for (int i = 0; i < 16; ++i) st[i] = 0.f;
        const int r = mt * 32 + l31;
#pragma unroll
        for (int kc = 0; kc < 4; ++kc) {
          short8 kf =
              *(const short8*)&Ks[cur][r * 64 + (((kc * 2 + hl) ^ (r & 7)) * 8)];
          st = __builtin_amdgcn_mfma_f32_32x32x16_bf16(kf, qf[qs][kc], st, 0, 0, 0);
        }
        // C layout: col=q=l31, row=kv_local = (reg&3)+8*(reg>>2)+4*hl
#pragma unroll
        for (int g = 0; g < 4; ++g) {
          float v0 = st[4 * g + 0]; v0 = v0 > 0.f ? v0 : 0.f;
          float v1 = st[4 * g + 1]; v1 = v1 > 0.f ? v1 : 0.f;
          float v2 = st[4 * g + 2]; v2 = v2 > 0.f ? v2 : 0.f;
          float v3 = st[4 * g + 3]; v3 = v3 > 0.f ? v3 : 0.f;
          den[qs] += (v0 + v1) + (v2 + v3);
          uint2 u;
          u.x = pkbf(v0, v1);
          u.y = pkbf(v2, v3);
          *(uint2*)&PW[l31 * 72 + mt * 32 + g * 8 + hl * 4] = u;
        }
      }
      // PV (same-wave LDS RAW: DS ops execute in order)
      short8 pa[4];
#pragma unroll
      for (int kc = 0; kc < 4; ++kc)
        pa[kc] = *(const short8*)&PW[l31 * 72 + kc * 16 + hl * 8];
#pragma unroll
      for (int dt = 0; dt < 2; ++dt)
#pragma unroll
        for (int kc = 0; kc < 4; ++kc)
          octx[qs][dt] = __builtin_amdgcn_mfma_f32_32x32x16_bf16(
              pa[kc], vf[dt][kc], octx[qs][dt], 0, 0, 0);
    }
  }

  // denominators: each lane has half the kv rows for q=l31 -> fold halves
#pragma unroll
  for (int qs = 0; qs < 2; ++qs) den[qs] += __shfl_xor(den[qs], 32);
  // Ks[0] last read at kv=14; every wave passed kv=15's barrier since -> safe.
  // Writes/reads below are wave-private (region w), same-wave DS in order.
  float* dsc = (float*)&Ks[0][0];    // 256 floats scale scratch
  if (hl == 0) {
    dsc[w * 64 + l31]      = 1.f / (den[0] + 8e-6f);  // folded 1/sqrt(64)
    dsc[w * 64 + 32 + l31] = 1.f / (den[1] + 8e-6f);
  }

#pragma unroll
  for (int qs = 0; qs < 2; ++qs)
#pragma unroll
    for (int dt = 0; dt < 2; ++dt)
#pragma unroll
      for (int reg = 0; reg < 16; ++reg) {
        const int qrow = (reg & 3) + 8 * (reg >> 2) + 4 * hl;
        const float sc = dsc[w * 64 + qs * 32 + qrow];
        const size_t grow =
            (size_t)(tb * 1024 + qt * 256 + w * 64 + qs * 32 + qrow);
        ctx[grow * 768 + h * 64 + dt * 32 + l31] = f2bf(octx[qs][dt][reg] * sc);
      }
}

// ---------------------------------------------------------------------------
extern "C" void kernel_launch(void* const* d_in, const int* in_sizes, int n_in,
                              void* d_out, int out_size, void* d_ws, size_t ws_size,
                              hipStream_t stream) {
  const float* x  = (const float*)d_in[0];
  const float* Wq = (const float*)d_in[1];
  const float* bq = (const float*)d_in[2];
  const float* Wk = (const float*)d_in[3];
  const float* bk = (const float*)d_in[4];
  const float* Wv = (const float*)d_in[5];
  const float* bv = (const float*)d_in[6];
  const float* Wo = (const float*)d_in[7];
  const float* bo = (const float*)d_in[8];
  float* out = (float*)d_out;

  char* ws = (char*)d_ws;
  // workspace layout (bytes); CTX aliases XBF (XBF dead after QKV GEMM)
  unsigned short* XBF  = (unsigned short*)(ws);                  // 25165824 B
  unsigned short* CTX  = (unsigned short*)(ws);                  // alias
  unsigned short* WQKV = (unsigned short*)(ws + 25165824);       //  3538944 B
  unsigned short* WOb  = (unsigned short*)(ws + 28704768);       //  1179648 B
  unsigned short* QKV  = (unsigned short*)(ws + 29884416);       // 75497472 B
  unsigned short* VT   = (unsigned short*)(ws + 105381888);      // 25165824 B
  // total: 130547712 B

  cast4<<<12288, 256, 0, stream>>>(x, XBF, 3145728);
  cast4<<<576, 256, 0, stream>>>(Wq, WQKV, 147456);
  cast4<<<576, 256, 0, stream>>>(Wk, WQKV + 589824, 147456);
  cast4<<<576, 256, 0, stream>>>(Wv, WQKV + 1179648, 147456);
  cast4<<<576, 256, 0, stream>>>(Wo, WOb, 147456);

  gemm_bt<true><<<dim3(18, 128), 256, 0, stream>>>(XBF, WQKV, QKV, nullptr,
                                                   bq, bk, bv, 2304);
  transpose_v<<<3072, 256, 0, stream>>>(QKV, VT);
  attn32<<<dim3(4, 192), 256, 0, stream>>>(QKV, VT, CTX);
  gemm_bt<false><<<dim3(6, 128), 256, 0, stream>>>(CTX, WOb, nullptr, out,
                                                   bo, bo, bo, 768);
}

// Round 4
// 333.875 us; speedup vs baseline: 1.1838x; 1.1838x over previous
//
#include <hip/hip_runtime.h>
#include <hip/hip_bf16.h>
#include <cstdint>

// ---------------------------------------------------------------------------
// TempoSpikeSelfAttention on MI355X (gfx950), bf16-MFMA pipeline.
//   dims: T=4 B=4 N=1024 D=768 H=12 Dh=64 -> M = T*B*N = 16384 rows
// Pipeline:
//   1. cast x, Wq|Wk|Wv (concat), Wo to bf16
//   2. QKV GEMM (m97 structure): QKV[16384, 2304] bf16, bias fused
//   3. transpose V -> Vt[(tb*12+h)*64 + d][1024]  (per-head d-major)
//   4. attn32 v4: grid (192 heads, 4 qt) so same-head blocks share an XCD/L2;
//      256 q/block, wave = 64 q (2 subtiles of 32). Register-pipelined K/V
//      staging (loads for kv+1 issued after barrier#2, drained at barrier#1).
//      S^T = K Q^T (mfma 32x32x16); P converted C-layout -> B-operand layout
//      IN REGISTERS via v_permlane32_swap_b32 (no LDS round-trip);
//      octx += V^T P (ctx C-layout col=q); L1-normalize in regs at end.
//   5. O GEMM: out = CTX @ Wo^T + bo  -> fp32 d_out
// ---------------------------------------------------------------------------

typedef __attribute__((ext_vector_type(8))) short short8;     // 8 bf16 = 4 VGPR
typedef __attribute__((ext_vector_type(4))) float float4v;    // 16x16 acc
typedef __attribute__((ext_vector_type(16))) float float16v;  // 32x32 acc

__device__ __forceinline__ unsigned short f2bf(float f) {
  unsigned int u = __float_as_uint(f);
  u = (u + 0x7fffu + ((u >> 16) & 1u)) >> 16;   // RNE
  return (unsigned short)u;
}

// pack two f32 -> two bf16 (round-half-away) in one v_perm_b32
__device__ __forceinline__ unsigned int pkbf(float a, float b) {
  unsigned int ua = __float_as_uint(a) + 0x8000u;
  unsigned int ub = __float_as_uint(b) + 0x8000u;
  return __builtin_amdgcn_perm(ub, ua, 0x07060302u);  // [bf(a) lo16 | bf(b) hi16]
}

// async global->LDS, 16B per lane; LDS dest = wave-uniform base + lane*16
__device__ __forceinline__ void gld_lds16(const void* g, void* lds) {
  __builtin_amdgcn_global_load_lds(
      (__attribute__((address_space(1))) void*)(uintptr_t)g,
      (__attribute__((address_space(3))) void*)(uint32_t)(uintptr_t)lds,
      16, 0, 0);
}

// ---------------------------------------------------------------------------
__global__ __launch_bounds__(256) void cast4(const float* __restrict__ src,
                                             unsigned short* __restrict__ dst,
                                             int n4) {
  int i = blockIdx.x * 256 + threadIdx.x;
  if (i >= n4) return;
  float4 f = reinterpret_cast<const float4*>(src)[i];
  ushort4 o;
  o.x = f2bf(f.x); o.y = f2bf(f.y); o.z = f2bf(f.z); o.w = f2bf(f.w);
  reinterpret_cast<ushort4*>(dst)[i] = o;
}

// ---------------------------------------------------------------------------
// C[i,j] = sum_k A[i,k] * Bt[j,k] + bias[j].  K=768 fixed. 128x128 tile, BK=32.
// 4 waves in 2x2, each 64x64 (4x4 mfma 16x16x32 tiles).
template <bool OUT_BF16>
__global__ __launch_bounds__(256) void gemm_bt(
    const unsigned short* __restrict__ A,   // [M,768] bf16
    const unsigned short* __restrict__ Bt,  // [N,768] bf16
    unsigned short* __restrict__ Cb,        // bf16 out [M,N]
    float* __restrict__ Cf,                 // f32 out  [M,N]
    const float* __restrict__ b0, const float* __restrict__ b1,
    const float* __restrict__ b2, int N) {
  constexpr int K = 768;
  __shared__ unsigned short As[128 * 32];   // packed: row stride 32 el (64 B)
  __shared__ unsigned short Bs[128 * 32];

  const int tid = threadIdx.x;
  const int lane = tid & 63;
  const int w = tid >> 6;
  const int wrow = w >> 1, wcol = w & 1;
  const int l15 = lane & 15, quad = lane >> 4;
  const int i0 = blockIdx.y * 128, j0 = blockIdx.x * 128;

  const unsigned short* ga = A + (size_t)(i0 + 32 * w + (lane >> 2)) * K + (lane & 3) * 8;
  const unsigned short* gb = Bt + (size_t)(j0 + 32 * w + (lane >> 2)) * K + (lane & 3) * 8;

  float4v acc[4][4];
#pragma unroll
  for (int a = 0; a < 4; ++a)
#pragma unroll
    for (int b = 0; b < 4; ++b) acc[a][b] = float4v{0.f, 0.f, 0.f, 0.f};

#pragma unroll 1
  for (int kt = 0; kt < K / 32; ++kt) {
    const unsigned short* pa = ga + kt * 32;
    const unsigned short* pb = gb + kt * 32;
    gld_lds16(pa, &As[(32 * w) * 32]);
    gld_lds16(pa + 16 * K, &As[(32 * w + 16) * 32]);
    gld_lds16(pb, &Bs[(32 * w) * 32]);
    gld_lds16(pb + 16 * K, &Bs[(32 * w + 16) * 32]);
    __syncthreads();   // drains vmcnt before barrier -> LDS tiles ready

    short8 af[4], bfr[4];
#pragma unroll
    for (int a = 0; a < 4; ++a)
      af[a] = *(const short8*)&As[(wrow * 64 + a * 16 + l15) * 32 + quad * 8];
#pragma unroll
    for (int b = 0; b < 4; ++b)
      bfr[b] = *(const short8*)&Bs[(wcol * 64 + b * 16 + l15) * 32 + quad * 8];
#pragma unroll
    for (int a = 0; a < 4; ++a)
#pragma unroll
      for (int b = 0; b < 4; ++b)
        acc[a][b] = __builtin_amdgcn_mfma_f32_16x16x32_bf16(af[a], bfr[b], acc[a][b], 0, 0, 0);
    __syncthreads();   // all reads done before next stage overwrites
  }

  const int sel = j0 / 768;
  const float* bp = (sel == 0) ? b0 : ((sel == 1) ? b1 : b2);
#pragma unroll
  for (int a = 0; a < 4; ++a) {
    const int row0 = i0 + wrow * 64 + a * 16 + quad * 4;
#pragma unroll
    for (int b = 0; b < 4; ++b) {
      const int col = j0 + wcol * 64 + b * 16 + l15;
      const float bias = bp[col - sel * 768];
#pragma unroll
      for (int r = 0; r < 4; ++r) {
        const float v = acc[a][b][r] + bias;
        if (OUT_BF16)
          Cb[(size_t)(row0 + r) * N + col] = f2bf(v);
        else
          Cf[(size_t)(row0 + r) * N + col] = v;
      }
    }
  }
}

// ---------------------------------------------------------------------------
// Vt[(tb*12+h)*64 + d][n] = QKV[(tb*1024+n)*2304 + 1536 + h*64 + d]
__global__ __launch_bounds__(256) void transpose_v(
    const unsigned short* __restrict__ qkv, unsigned short* __restrict__ vt) {
  __shared__ unsigned short T[64 * 72];
  const int bz = blockIdx.x;        // 192*16
  const int nt = bz & 15;
  const int tbh = bz >> 4;
  const int tb = tbh / 12, h = tbh % 12;
  const int tid = threadIdx.x;
#pragma unroll
  for (int it = 0; it < 2; ++it) {
    int c = tid + it * 256;
    int row = c >> 3, d0 = (c & 7) * 8;
    const unsigned short* g =
        qkv + (size_t)(tb * 1024 + nt * 64 + row) * 2304 + 1536 + h * 64 + d0;
    *(uint4*)&T[row * 72 + d0] = *(const uint4*)g;
  }
  __syncthreads();
#pragma unroll
  for (int it = 0; it < 2; ++it) {
    int c = tid + it * 256;
    int d = c >> 3, n0 = (c & 7) * 8;
    unsigned short tmp[8];
#pragma unroll
    for (int i = 0; i < 8; ++i) tmp[i] = T[(n0 + i) * 72 + d];
    *(uint4*)&vt[((size_t)(tb * 12 + h) * 64 + d) * 1024 + nt * 64 + n0] =
        *(uint4*)tmp;
  }
}

// ---------------------------------------------------------------------------
// Attention v4. Grid (tbh=192, qt=4); 256 thr = 4 waves; wave = 64 q (2 x 32).
// Per kv-tile (64 keys):
//   barrier#1 (drains loads of kv) -> ds_write staged regs -> barrier#2 ->
//   issue loads kv+1 (hidden under compute) -> compute:
//     S^T = K.Q^T  (A=K rows from LDS, B=Q regs; C: row=kv, col=q=l31)
//     relu -> den (reg, q=l31); pack bf16; permlane32_swap -> PV B-frags
//     octx += V^T.P (A=Vt rows from LDS, B=P frags; C: row=d, col=q=l31)
// No P LDS traffic, no normalization scratch.
__global__ __launch_bounds__(256) void attn32(
    const unsigned short* __restrict__ qkv,  // [16384, 2304] bf16
    const unsigned short* __restrict__ vt,   // [(tbh)*64 + d][1024] bf16
    unsigned short* __restrict__ ctx) {      // [16384, 768] bf16
  __shared__ unsigned short Ks[64 * 72];     // [kv_local][d], padded
  __shared__ unsigned short Vs[64 * 72];     // [d][kv_local], padded

  const int tbh = blockIdx.x;                // same-head blocks: ids 192 apart
  const int qt = blockIdx.y;                 // -> same XCD (192 % 8 == 0)
  const int tb = tbh / 12, h = tbh % 12;
  const int tid = threadIdx.x, lane = tid & 63, w = tid >> 6;
  const int l31 = lane & 31, hl = lane >> 5;

  // ---- Q fragments: one-time scattered global loads ----
  short8 qf[2][4];   // [qs][kc]: B-op: lane holds Q[q=.. +l31][kc*16+hl*8+j]
#pragma unroll
  for (int qs = 0; qs < 2; ++qs) {
    const unsigned short* qp =
        qkv + (size_t)(tb * 1024 + qt * 256 + w * 64 + qs * 32 + l31) * 2304 +
        h * 64 + hl * 8;
#pragma unroll
    for (int kc = 0; kc < 4; ++kc) qf[qs][kc] = *(const short8*)(qp + kc * 16);
  }

  // ---- staging: 256 thr cover 64 rows x 8 chunks of 16B, 2 rows/thread ----
  const int srow = tid >> 3;   // 0..31 (and +32)
  const int sblk = tid & 7;
  const unsigned short* kcol =
      qkv + (size_t)(tb * 1024) * 2304 + 768 + h * 64 + sblk * 8;
  const unsigned short* vcol = vt + ((size_t)tbh * 64 + srow) * 1024 + sblk * 8;
  uint4 kr0, kr1, vr0, vr1;
  auto loadKV = [&](int kv) {
    const unsigned short* kp = kcol + (size_t)(kv * 64 + srow) * 2304;
    kr0 = *(const uint4*)kp;
    kr1 = *(const uint4*)(kp + 32 * 2304);
    const unsigned short* vp = vcol + kv * 64;
    vr0 = *(const uint4*)vp;
    vr1 = *(const uint4*)(vp + 32 * 1024);
  };

  float16v octx[2][2];   // [qs][dt]; C: row=d_local, col=q=l31
#pragma unroll
  for (int qs = 0; qs < 2; ++qs)
#pragma unroll
    for (int dt = 0; dt < 2; ++dt)
#pragma unroll
      for (int i = 0; i < 16; ++i) octx[qs][dt][i] = 0.f;
  float den[2] = {0.f, 0.f};

  loadKV(0);

#pragma unroll 1
  for (int kv = 0; kv < 16; ++kv) {
    __syncthreads();   // #1: all reads of tile kv-1 done; drains loads of kv
    *(uint4*)&Ks[srow * 72 + sblk * 8] = kr0;
    *(uint4*)&Ks[(srow + 32) * 72 + sblk * 8] = kr1;
    *(uint4*)&Vs[srow * 72 + sblk * 8] = vr0;
    *(uint4*)&Vs[(srow + 32) * 72 + sblk * 8] = vr1;
    __syncthreads();   // #2: writes visible (vmcnt trivially 0 here)
    if (kv < 15) loadKV(kv + 1);   // in flight across compute below

#pragma unroll
    for (int qs = 0; qs < 2; ++qs) {
      // S^T = K.Q^T, then relu+den+pack (C: col=q=l31, row=kv=4hl+(r)+8g+32mt)
      unsigned int pk[2][8];   // [mt][g*2+p]
#pragma unroll
      for (int mt = 0; mt < 2; ++mt) {
        float16v st;
#pragma unroll
        for (int i = 0; i < 16; ++i) st[i] = 0.f;
#pragma unroll
        for (int kc = 0; kc < 4; ++kc) {
          short8 kf =
              *(const short8*)&Ks[(mt * 32 + l31) * 72 + kc * 16 + hl * 8];
          st = __builtin_amdgcn_mfma_f32_32x32x16_bf16(kf, qf[qs][kc], st, 0, 0, 0);
        }
#pragma unroll
        for (int g = 0; g < 4; ++g) {
          float v0 = st[4 * g + 0]; v0 = v0 > 0.f ? v0 : 0.f;
          float v1 = st[4 * g + 1]; v1 = v1 > 0.f ? v1 : 0.f;
          float v2 = st[4 * g + 2]; v2 = v2 > 0.f ? v2 : 0.f;
          float v3 = st[4 * g + 3]; v3 = v3 > 0.f ? v3 : 0.f;
          den[qs] += (v0 + v1) + (v2 + v3);
          pk[mt][g * 2 + 0] = pkbf(v0, v1);
          pk[mt][g * 2 + 1] = pkbf(v2, v3);
        }
      }
      // C-layout -> PV B-operand layout entirely in registers:
      // B-frag[kc] lane(l31,hl) needs kv = kc*16 + hl*8 + j at q=l31.
      // X=pk[mt][gb*2+p], Y=pk[mt][(gb+1)*2+p]; permlane32_swap gives
      // X'={X.lo,Y.lo} (j=2p,2p+1), Y'={X.hi,Y.hi} (j=2p+4,2p+5).
#pragma unroll
      for (int kc = 0; kc < 4; ++kc) {
        const int mt = kc >> 1, gb = (kc & 1) * 2;
        unsigned int a0 = pk[mt][gb * 2 + 0], b0 = pk[mt][gb * 2 + 2];
        unsigned int a1 = pk[mt][gb * 2 + 1], b1 = pk[mt][gb * 2 + 3];
        asm("v_permlane32_swap_b32 %0, %1" : "+v"(a0), "+v"(b0));
        asm("v_permlane32_swap_b32 %0, %1" : "+v"(a1), "+v"(b1));
        union { unsigned int u[4]; short8 s; } pf;
        pf.u[0] = a0; pf.u[1] = a1; pf.u[2] = b0; pf.u[3] = b1;
#pragma unroll
        for (int dt = 0; dt < 2; ++dt) {
          short8 vb =
              *(const short8*)&Vs[(dt * 32 + l31) * 72 + kc * 16 + hl * 8];
          octx[qs][dt] = __builtin_amdgcn_mfma_f32_32x32x16_bf16(
              vb, pf.s, octx[qs][dt], 0, 0, 0);
        }
      }
    }
  }

  // ---- normalize + store; lane l31 owns q, all in registers ----
#pragma unroll
  for (int qs = 0; qs < 2; ++qs) {
    float d = den[qs] + __shfl_xor(den[qs], 32);
    const float sc = 1.f / (d + 8e-6f);   // folded 1/sqrt(64) scaling
    const size_t qrow = (size_t)(tb * 1024 + qt * 256 + w * 64 + qs * 32 + l31);
#pragma unroll
    for (int dt = 0; dt < 2; ++dt)
#pragma unroll
      for (int g = 0; g < 4; ++g) {
        const float v0 = octx[qs][dt][4 * g + 0] * sc;
        const float v1 = octx[qs][dt][4 * g + 1] * sc;
        const float v2 = octx[qs][dt][4 * g + 2] * sc;
        const float v3 = octx[qs][dt][4 * g + 3] * sc;
        uint2 u;
        u.x = pkbf(v0, v1);
        u.y = pkbf(v2, v3);
        *(uint2*)&ctx[qrow * 768 + h * 64 + dt * 32 + g * 8 + hl * 4] = u;
      }
  }
}

// ---------------------------------------------------------------------------
extern "C" void kernel_launch(void* const* d_in, const int* in_sizes, int n_in,
                              void* d_out, int out_size, void* d_ws, size_t ws_size,
                              hipStream_t stream) {
  const float* x  = (const float*)d_in[0];
  const float* Wq = (const float*)d_in[1];
  const float* bq = (const float*)d_in[2];
  const float* Wk = (const float*)d_in[3];
  const float* bk = (const float*)d_in[4];
  const float* Wv = (const float*)d_in[5];
  const float* bv = (const float*)d_in[6];
  const float* Wo = (const float*)d_in[7];
  const float* bo = (const float*)d_in[8];
  float* out = (float*)d_out;

  char* ws = (char*)d_ws;
  // workspace layout (bytes); CTX aliases XBF (XBF dead after QKV GEMM)
  unsigned short* XBF  = (unsigned short*)(ws);                  // 25165824 B
  unsigned short* CTX  = (unsigned short*)(ws);                  // alias
  unsigned short* WQKV = (unsigned short*)(ws + 25165824);       //  3538944 B
  unsigned short* WOb  = (unsigned short*)(ws + 28704768);       //  1179648 B
  unsigned short* QKV  = (unsigned short*)(ws + 29884416);       // 75497472 B
  unsigned short* VT   = (unsigned short*)(ws + 105381888);      // 25165824 B
  // total: 130547712 B

  cast4<<<12288, 256, 0, stream>>>(x, XBF, 3145728);
  cast4<<<576, 256, 0, stream>>>(Wq, WQKV, 147456);
  cast4<<<576, 256, 0, stream>>>(Wk, WQKV + 589824, 147456);
  cast4<<<576, 256, 0, stream>>>(Wv, WQKV + 1179648, 147456);
  cast4<<<576, 256, 0, stream>>>(Wo, WOb, 147456);

  gemm_bt<true><<<dim3(18, 128), 256, 0, stream>>>(XBF, WQKV, QKV, nullptr,
                                                   bq, bk, bv, 2304);
  transpose_v<<<3072, 256, 0, stream>>>(QKV, VT);
  attn32<<<dim3(192, 4), 256, 0, stream>>>(QKV, VT, CTX);
  gemm_bt<false><<<dim3(6, 128), 256, 0, stream>>>(CTX, WOb, nullptr, out,
                                                   bo, bo, bo, 768);
}